// Round 5
// baseline (249.886 us; speedup 1.0000x reference)
//
#include <hip/hip_runtime.h>
#include <hip/hip_bf16.h>
#include <hip/hip_fp16.h>

#define N_NODES 50000
#define N_EDGES 800000
#define NTILES 3125        // N_NODES / 16
#define W_TOTAL 57344      // packed bf16 weight elements (W1 slot unused)
#define WB2 192            // pack blocks (W2..A4b = 49152 elems)
#define SCAT 512           // scatter blocks
#define SSTRIDE (SCAT * 256)
#define TB 782             // layer1/dense MFMA blocks (4 waves each)
#define ROWCAP 64          // padded-CSR slots per node (deg mean 16, 12-sigma safe)
#define ZROW N_NODES       // index of the all-zero fp8 row used for slot padding

typedef __attribute__((ext_vector_type(8))) short bf16x8;          // MFMA A/B frag
typedef __attribute__((ext_vector_type(4))) float f32x4;           // MFMA C/D frag
typedef __attribute__((ext_vector_type(2))) float f32x2;           // packed f32 pair
typedef __attribute__((ext_vector_type(8))) unsigned short u16x8;  // 16B load/store
typedef __attribute__((ext_vector_type(4))) unsigned int u32x4;    // 16B load (ext-vec for nt builtins)

__device__ inline unsigned short f2bf(float f) {  // round-to-nearest-even
    unsigned int x = __float_as_uint(f);
    unsigned int r = (x + 0x7FFF + ((x >> 16) & 1)) >> 16;
    return (unsigned short)r;
}
__device__ inline float2 h2f2(unsigned int u) {   // packed half2 -> float2
    __half2 h = *(__half2*)&u;
    return make_float2(__low2float(h), __high2float(h));
}
__device__ inline unsigned int f22h2(float a, float b) {  // 2 floats -> packed half2
    __half2 h = __floats2half2_rn(a, b);
    return *(unsigned int*)&h;
}

// ---------------------------------------------------------------------------
// SCATTER (R4: isolated into its own kernel for rocprof visibility).
// 4-way batched: 4 independent dst loads -> 4 independent atomicAdds (in
// flight together) -> 4 stores. If the old 52us was per-wave atomic-return
// serialization, this collapses it; if it is chip-level atomic throughput,
// duration is unchanged and the theory is decided either way.
__global__ __launch_bounds__(256) void scatter_k(const int* __restrict__ src,
                                                 const int* __restrict__ dst,
                                                 int* __restrict__ cnt,
                                                 unsigned short* __restrict__ srcAp) {
    int t0 = blockIdx.x * 256 + threadIdx.x;
    for (int base = t0; base < N_EDGES; base += 4 * SSTRIDE) {
        int e0 = base;
        int e1 = base + SSTRIDE;
        int e2 = base + 2 * SSTRIDE;
        int e3 = base + 3 * SSTRIDE;
        int d0 = dst[e0];                       // e0 < N_EDGES by loop condition
        int d1 = (e1 < N_EDGES) ? dst[e1] : -1;
        int d2 = (e2 < N_EDGES) ? dst[e2] : -1;
        int d3 = (e3 < N_EDGES) ? dst[e3] : -1;
        int s0 = src[e0];
        int s1 = (e1 < N_EDGES) ? src[e1] : 0;
        int s2 = (e2 < N_EDGES) ? src[e2] : 0;
        int s3 = (e3 < N_EDGES) ? src[e3] : 0;
        int p0 = atomicAdd(&cnt[d0], 1);
        int p1 = (d1 >= 0) ? atomicAdd(&cnt[d1], 1) : ROWCAP;
        int p2 = (d2 >= 0) ? atomicAdd(&cnt[d2], 1) : ROWCAP;
        int p3 = (d3 >= 0) ? atomicAdd(&cnt[d3], 1) : ROWCAP;
        if (p0 < ROWCAP) srcAp[(size_t)d0 * ROWCAP + p0] = (unsigned short)s0;
        if (p1 < ROWCAP) srcAp[(size_t)d1 * ROWCAP + p1] = (unsigned short)s1;
        if (p2 < ROWCAP) srcAp[(size_t)d2 * ROWCAP + p2] = (unsigned short)s2;
        if (p3 < ROWCAP) srcAp[(size_t)d3 * ROWCAP + p3] = (unsigned short)s3;
    }
}

// ---------------------------------------------------------------------------
// LAYER1 + PACK (R4: scatter removed; otherwise identical to pass1).
//  [0, TB)    : layer1 MFMA, W1 converted fp32->bf16 inline; writes UNSCALED
//               h (fp16) to Ht.
//  [TB, end)  : bf16-pack W2..A4b into wpAll[8192..].
__global__ __launch_bounds__(256) void mfma1_k(
    const float* __restrict__ x,
    const float* __restrict__ W1, const float* __restrict__ b1,
    const float* W2, const float* A2a, const float* A2b,
    const float* W3, const float* A3a, const float* A3b,
    const float* W4, const float* A4a, const float* A4b,
    unsigned short* __restrict__ wp, __half* __restrict__ Ht) {
    int tid = threadIdx.x;

    if (blockIdx.x >= TB) {                       // ---- pack W2..A4b ----
        int i = 8192 + (blockIdx.x - TB) * 256 + tid;
        if (i >= W_TOTAL) return;
        float v;
        if (i < 16384)      v = W2[i - 8192];
        else if (i < 20480) v = A2a[i - 16384];
        else if (i < 24576) v = A2b[i - 20480];
        else if (i < 32768) v = W3[i - 24576];
        else if (i < 36864) v = A3a[i - 32768];
        else if (i < 40960) v = A3b[i - 36864];
        else if (i < 49152) v = W4[i - 40960];
        else if (i < 53248) v = A4a[i - 49152];
        else                v = A4b[i - 53248];
        wp[i] = f2bf(v);
        return;
    }

    // ---- layer1: h = relu(x @ W1^T + b1) -> Ht (fp16, unscaled) ----
    int wave = (blockIdx.x * 256 + tid) >> 6;
    if (wave >= NTILES) return;
    int lane = tid & 63;
    int r16 = lane & 15, quad = lane >> 4;
    int base = wave * 16;

    bf16x8 a[4];
    const float* xr = x + (size_t)(base + r16) * 128 + quad * 8;
#pragma unroll
    for (int kb = 0; kb < 4; kb++) {
        float4 f0 = *(const float4*)(xr + kb * 32);
        float4 f1 = *(const float4*)(xr + kb * 32 + 4);
        bf16x8 v;
        v[0] = (short)f2bf(f0.x); v[1] = (short)f2bf(f0.y);
        v[2] = (short)f2bf(f0.z); v[3] = (short)f2bf(f0.w);
        v[4] = (short)f2bf(f1.x); v[5] = (short)f2bf(f1.y);
        v[6] = (short)f2bf(f1.z); v[7] = (short)f2bf(f1.w);
        a[kb] = v;
    }

#pragma unroll
    for (int jt = 0; jt < 4; jt++) {
        f32x4 acc = {0.f, 0.f, 0.f, 0.f};
        const float* wr = W1 + (size_t)(jt * 16 + r16) * 128 + quad * 8;
#pragma unroll
        for (int kb = 0; kb < 4; kb++) {
            float4 g0 = *(const float4*)(wr + kb * 32);
            float4 g1 = *(const float4*)(wr + kb * 32 + 4);
            bf16x8 b;
            b[0] = (short)f2bf(g0.x); b[1] = (short)f2bf(g0.y);
            b[2] = (short)f2bf(g0.z); b[3] = (short)f2bf(g0.w);
            b[4] = (short)f2bf(g1.x); b[5] = (short)f2bf(g1.y);
            b[6] = (short)f2bf(g1.z); b[7] = (short)f2bf(g1.w);
            acc = __builtin_amdgcn_mfma_f32_16x16x32_bf16(a[kb], b, acc, 0, 0, 0);
        }
        int col = jt * 16 + r16;
        float bias = b1[col];
#pragma unroll
        for (int r = 0; r < 4; r++) {
            int row = base + quad * 4 + r;
            float v = fmaxf(acc[r] + bias, 0.f);
            Ht[(size_t)row * 64 + col] = __float2half(v);
        }
    }
}

// ---------------------------------------------------------------------------
// scale: isq/sdeg from cnt; As = Ht * isq (fp16); As8 = Ht * isq (fp8 e4m3,
// gather-only copy). Also fills padded-CSR slots [cv, ceil8(cv)) with ZROW so
// the conv loop needs no per-edge masking (ZROW row of fp8 buffers is zero).
// 16 threads per row.
__global__ __launch_bounds__(256) void scale_kernel(const int* __restrict__ cnt,
                                                    const __half* __restrict__ Ht,
                                                    __half* __restrict__ As,
                                                    unsigned char* __restrict__ As8,
                                                    unsigned short* __restrict__ srcAp,
                                                    float* __restrict__ isq,
                                                    float* __restrict__ sdeg) {
    int t = blockIdx.x * 256 + threadIdx.x;
    int row = t >> 4, sl = t & 15;
    if (row >= N_NODES) return;
    int c = cnt[row];
    float dv = fmaxf((float)c, 1.0f);
    float is = rsqrtf(dv);
    if (sl == 0) {
        isq[row] = is;
        sdeg[row] = sqrtf(dv);
    }
    // pad CSR slots up to the next multiple of 8 with the zero-row index
    int cv = min(c, ROWCAP);
    int cvr = (cv + 7) & ~7;
    if (sl < cvr - cv) srcAp[(size_t)row * ROWCAP + cv + sl] = (unsigned short)ZROW;

    uint2 rv = *((const uint2*)(Ht + (size_t)row * 64) + sl);   // 4 halves
    float2 fa = h2f2(rv.x), fb = h2f2(rv.y);
    float s0 = fa.x * is, s1 = fa.y * is, s2 = fb.x * is, s3 = fb.y * is;
    uint2 ov;
    ov.x = f22h2(s0, s1);
    ov.y = f22h2(s2, s3);
    *((uint2*)(As + (size_t)row * 64) + sl) = ov;
    unsigned int w = __builtin_amdgcn_cvt_pk_fp8_f32(s0, s1, 0, false);
    w = __builtin_amdgcn_cvt_pk_fp8_f32(s2, s3, w, true);
    ((unsigned int*)As8)[(size_t)row * 16 + sl] = w;            // 4 fp8 bytes
}

// ---------------------------------------------------------------------------
// FUSED conv + dense, one block = 64 rows (4 MFMA tiles, wave-independent).
// conv: 16 rows x 4 feat-lanes, each lane gathers a 16B uint4 (quarter of the
//   64B fp8 row); one wave instruction covers 16 edges. Slot vectors are
//   prefetched one chunk ahead. Streaming accesses (srcAp, dense-phase fp16
//   reads, fp16/fp32 stores) are NONTEMPORAL to keep per-XCD L2 resident for
//   the 3.2 MB fp8 gather array.
// dense: fp16 path -- h A-frags reconstructed as bf16(fp16*sdeg), so fp8
//   error enters ONLY through the conv half of the concat.
__global__ __launch_bounds__(256) void conv_dense_k(const __half* __restrict__ hs,
                                                    const unsigned char* __restrict__ hs8,
                                                    const int* __restrict__ cnt,
                                                    const unsigned short* __restrict__ srcAp,
                                                    const float* __restrict__ isq,
                                                    const float* __restrict__ sdeg,
                                                    const unsigned short* __restrict__ wp,
                                                    const unsigned short* __restrict__ aap,
                                                    const unsigned short* __restrict__ abp,
                                                    __half* __restrict__ outs,
                                                    unsigned char* __restrict__ outs8,
                                                    float* __restrict__ outf,
                                                    int finalLayer) {
    __shared__ unsigned short clds[64][64];   // conv result (bf16), 8 KB
    int tid = threadIdx.x;
    int wv = tid >> 6;
    int lane = tid & 63;
    int t = blockIdx.x * 4 + wv;
    if (t >= NTILES) return;
    int base = t * 16;   // N_NODES % 16 == 0: all rows valid

    // ---- conv phase (no barrier: wave reads only its own clds quarter) ----
    {
        int r = lane >> 2, fl = lane & 3;      // 16 rows x 4 feat-lanes
        int row = base + r;
        int b = row * ROWCAP;
        int cv = min(cnt[row], ROWCAP);
        int cvr = (cv + 7) & ~7;               // slots [cv,cvr) = ZROW (zeros)
        f32x2 acc[8];
#pragma unroll
        for (int k = 0; k < 8; k++) acc[k] = (f32x2){0.f, 0.f};
        if (cvr) {
            u16x8 sv = __builtin_nontemporal_load((const u16x8*)(srcAp + b));
            for (int i = 0; i < cvr; i += 8) {
                u16x8 svn = sv;                // prefetch next slot vector
                if (i + 8 < cvr)
                    svn = __builtin_nontemporal_load((const u16x8*)(srcAp + b + i + 8));
                u32x4 rv[8];
#pragma unroll
                for (int u = 0; u < 8; u++)
                    rv[u] = *((const u32x4*)(hs8 + (size_t)(int)sv[u] * 64) + fl);
#pragma unroll
                for (int u = 0; u < 8; u++) {
                    acc[0] += __builtin_amdgcn_cvt_pk_f32_fp8(rv[u][0], false);
                    acc[1] += __builtin_amdgcn_cvt_pk_f32_fp8(rv[u][0], true);
                    acc[2] += __builtin_amdgcn_cvt_pk_f32_fp8(rv[u][1], false);
                    acc[3] += __builtin_amdgcn_cvt_pk_f32_fp8(rv[u][1], true);
                    acc[4] += __builtin_amdgcn_cvt_pk_f32_fp8(rv[u][2], false);
                    acc[5] += __builtin_amdgcn_cvt_pk_f32_fp8(rv[u][2], true);
                    acc[6] += __builtin_amdgcn_cvt_pk_f32_fp8(rv[u][3], false);
                    acc[7] += __builtin_amdgcn_cvt_pk_f32_fp8(rv[u][3], true);
                }
                sv = svn;
            }
        }
        float sc = isq[row];
        u16x8 o0, o1;
#pragma unroll
        for (int k = 0; k < 4; k++) {
            o0[2 * k]     = f2bf(acc[k][0] * sc);
            o0[2 * k + 1] = f2bf(acc[k][1] * sc);
            o1[2 * k]     = f2bf(acc[4 + k][0] * sc);
            o1[2 * k + 1] = f2bf(acc[4 + k][1] * sc);
        }
        // lane (r,fl) owns feats [fl*16, fl*16+16) of its row
        *(u16x8*)(&clds[wv * 16 + r][fl * 16]) = o0;
        *(u16x8*)(&clds[wv * 16 + r][fl * 16 + 8]) = o1;
    }

    // ---- dense phase ----
    int r16 = lane & 15, quad = lane >> 4;
    float rs = sdeg[base + r16];                 // h = hs * sqrt(deg), per A-row
    const u32x4* hp = (const u32x4*)(hs + (size_t)(base + r16) * 64);
    u32x4 raw0 = __builtin_nontemporal_load(hp + quad);      // feats quad*8 .. +8
    u32x4 raw1 = __builtin_nontemporal_load(hp + 4 + quad);  // feats 32+quad*8 .. +8
    bf16x8 ha0, ha1;
    {
        float2 f;
        f = h2f2(raw0[0]); ha0[0] = (short)f2bf(f.x * rs); ha0[1] = (short)f2bf(f.y * rs);
        f = h2f2(raw0[1]); ha0[2] = (short)f2bf(f.x * rs); ha0[3] = (short)f2bf(f.y * rs);
        f = h2f2(raw0[2]); ha0[4] = (short)f2bf(f.x * rs); ha0[5] = (short)f2bf(f.y * rs);
        f = h2f2(raw0[3]); ha0[6] = (short)f2bf(f.x * rs); ha0[7] = (short)f2bf(f.y * rs);
        f = h2f2(raw1[0]); ha1[0] = (short)f2bf(f.x * rs); ha1[1] = (short)f2bf(f.y * rs);
        f = h2f2(raw1[1]); ha1[2] = (short)f2bf(f.x * rs); ha1[3] = (short)f2bf(f.y * rs);
        f = h2f2(raw1[2]); ha1[4] = (short)f2bf(f.x * rs); ha1[5] = (short)f2bf(f.y * rs);
        f = h2f2(raw1[3]); ha1[6] = (short)f2bf(f.x * rs); ha1[7] = (short)f2bf(f.y * rs);
    }
    bf16x8 ca0 = *(const bf16x8*)(&clds[wv * 16 + r16][quad * 8]);
    bf16x8 ca1 = *(const bf16x8*)(&clds[wv * 16 + r16][32 + quad * 8]);

    float isq4[4];
    if (!finalLayer) {
#pragma unroll
        for (int r = 0; r < 4; r++) isq4[r] = isq[base + quad * 4 + r];
    }

#pragma unroll
    for (int jt = 0; jt < 4; jt++) {
        const unsigned short* wr = wp + (size_t)(jt * 16 + r16) * 128 + quad * 8;
        const unsigned short* ar = aap + (size_t)(jt * 16 + r16) * 64 + quad * 8;
        const unsigned short* br = abp + (size_t)(jt * 16 + r16) * 64 + quad * 8;
        f32x4 P = {0.f, 0.f, 0.f, 0.f};
        f32x4 Q = {0.f, 0.f, 0.f, 0.f};
        f32x4 R = {0.f, 0.f, 0.f, 0.f};
        P = __builtin_amdgcn_mfma_f32_16x16x32_bf16(ha0, *(const bf16x8*)(wr), P, 0, 0, 0);
        P = __builtin_amdgcn_mfma_f32_16x16x32_bf16(ha1, *(const bf16x8*)(wr + 32), P, 0, 0, 0);
        P = __builtin_amdgcn_mfma_f32_16x16x32_bf16(ca0, *(const bf16x8*)(wr + 64), P, 0, 0, 0);
        P = __builtin_amdgcn_mfma_f32_16x16x32_bf16(ca1, *(const bf16x8*)(wr + 96), P, 0, 0, 0);
        Q = __builtin_amdgcn_mfma_f32_16x16x32_bf16(ha0, *(const bf16x8*)(ar), Q, 0, 0, 0);
        Q = __builtin_amdgcn_mfma_f32_16x16x32_bf16(ha1, *(const bf16x8*)(ar + 32), Q, 0, 0, 0);
        R = __builtin_amdgcn_mfma_f32_16x16x32_bf16(ha0, *(const bf16x8*)(br), R, 0, 0, 0);
        R = __builtin_amdgcn_mfma_f32_16x16x32_bf16(ha1, *(const bf16x8*)(br + 32), R, 0, 0, 0);
        int col = jt * 16 + r16;
#pragma unroll
        for (int r = 0; r < 4; r++) {
            int row = base + quad * 4 + r;
            float v = fmaxf(P[r] + Q[r] * R[r], 0.f);
            if (finalLayer) {
                __builtin_nontemporal_store(v, &outf[(size_t)row * 64 + col]);
            } else {
                float vs = v * isq4[r];
                __half hv = __float2half(vs);
                __builtin_nontemporal_store(*(unsigned short*)&hv,
                                            (unsigned short*)outs + (size_t)row * 64 + col);
                unsigned int pb = __builtin_amdgcn_cvt_pk_fp8_f32(vs, vs, 0, false);
                outs8[(size_t)row * 64 + col] = (unsigned char)pb;  // cached: next layer gathers it
            }
        }
    }
}

// ---------------------------------------------------------------------------
extern "C" void kernel_launch(void* const* d_in, const int* in_sizes, int n_in,
                              void* d_out, int out_size, void* d_ws, size_t ws_size,
                              hipStream_t stream) {
    const float* x = (const float*)d_in[0];
    const int* edges = (const int*)d_in[1];
    const float* W1 = (const float*)d_in[2];
    const float* b1 = (const float*)d_in[3];
    const float* W2 = (const float*)d_in[4];
    const float* A2a = (const float*)d_in[5];
    const float* A2b = (const float*)d_in[6];
    const float* W3 = (const float*)d_in[7];
    const float* A3a = (const float*)d_in[8];
    const float* A3b = (const float*)d_in[9];
    const float* W4 = (const float*)d_in[10];
    const float* A4a = (const float*)d_in[11];
    const float* A4b = (const float*)d_in[12];
    float* out = (float*)d_out;

    const int* src = edges;
    const int* dst = edges + N_EDGES;

    char* p = (char*)d_ws;
    auto alloc = [&](size_t bytes) {
        char* r = p;
        p += (bytes + 255) & ~(size_t)255;
        return r;
    };
    int* cnt              = (int*)alloc(N_NODES * 4);
    float* isq            = (float*)alloc(N_NODES * 4);
    float* sdeg           = (float*)alloc(N_NODES * 4);
    unsigned short* srcAp = (unsigned short*)alloc((size_t)N_NODES * ROWCAP * 2);
    unsigned short* wpAll = (unsigned short*)alloc(W_TOTAL * 2);
    __half* Ht            = (__half*)alloc((size_t)N_NODES * 64 * 2);
    __half* As            = (__half*)alloc((size_t)N_NODES * 64 * 2);
    __half* Bs            = (__half*)alloc((size_t)N_NODES * 64 * 2);
    unsigned char* As8    = (unsigned char*)alloc((size_t)(N_NODES + 1) * 64);  // +zero row
    unsigned char* Bs8    = (unsigned char*)alloc((size_t)(N_NODES + 1) * 64);

    const unsigned short* W2p  = wpAll + 8192;
    const unsigned short* A2ap = wpAll + 16384;
    const unsigned short* A2bp = wpAll + 20480;
    const unsigned short* W3p  = wpAll + 24576;
    const unsigned short* A3ap = wpAll + 32768;
    const unsigned short* A3bp = wpAll + 36864;
    const unsigned short* W4p  = wpAll + 40960;
    const unsigned short* A4ap = wpAll + 49152;
    const unsigned short* A4bp = wpAll + 53248;

    hipMemsetAsync(cnt, 0, N_NODES * 4, stream);
    hipMemsetAsync(As8 + (size_t)ZROW * 64, 0, 64, stream);   // zero pad-row
    hipMemsetAsync(Bs8 + (size_t)ZROW * 64, 0, 64, stream);

    // ---- scatter (isolated for rocprof) ----
    scatter_k<<<SCAT, 256, 0, stream>>>(src, dst, cnt, srcAp);

    // ---- layer1 MFMA + weight pack ----
    mfma1_k<<<TB + WB2, 256, 0, stream>>>(
        x, W1, b1, W2, A2a, A2b, W3, A3a, A3b, W4, A4a, A4b, wpAll, Ht);

    // ---- scale: isq/sdeg + As/As8 = Ht*isq + CSR pad fill ----
    scale_kernel<<<(N_NODES * 16 + 255) / 256, 256, 0, stream>>>(
        cnt, Ht, As, As8, srcAp, isq, sdeg);

    // ---- layer 2: As -> Bs ----
    conv_dense_k<<<TB, 256, 0, stream>>>(As, As8, cnt, srcAp, isq, sdeg,
                                         W2p, A2ap, A2bp, Bs, Bs8, nullptr, 0);
    // ---- layer 3: Bs -> As ----
    conv_dense_k<<<TB, 256, 0, stream>>>(Bs, Bs8, cnt, srcAp, isq, sdeg,
                                         W3p, A3ap, A3bp, As, As8, nullptr, 0);
    // ---- layer 4: As -> out (fp32) ----
    conv_dense_k<<<TB, 256, 0, stream>>>(As, As8, cnt, srcAp, isq, sdeg,
                                         W4p, A4ap, A4bp, nullptr, nullptr, out, 1);
}

// Round 6
// 233.517 us; speedup vs baseline: 1.0701x; 1.0701x over previous
//
#include <hip/hip_runtime.h>
#include <hip/hip_bf16.h>
#include <hip/hip_fp16.h>

#define N_NODES 50000
#define N_EDGES 800000
#define NTILES 3125        // N_NODES / 16
#define W_TOTAL 57344      // packed bf16 weight elements (W1 slot unused)
#define WB2 192            // pack blocks (W2..A4b = 49152 elems)
#define SCAT 512           // scatter blocks
#define TB 782             // layer1/dense MFMA blocks (4 waves each)
#define ROWCAP 64          // compacted slots per node (deg mean 16, 12-sigma safe)
#define SUBCAP 16          // per-XCD slots per node (deg/XCD mean 2, P(>16)~1e-11)
#define NXCD 8
#define ZROW N_NODES       // index of the all-zero fp8 row used for slot padding

typedef __attribute__((ext_vector_type(8))) short bf16x8;          // MFMA A/B frag
typedef __attribute__((ext_vector_type(4))) float f32x4;           // MFMA C/D frag
typedef __attribute__((ext_vector_type(2))) float f32x2;           // packed f32 pair
typedef __attribute__((ext_vector_type(8))) unsigned short u16x8;  // 16B load/store
typedef __attribute__((ext_vector_type(4))) unsigned int u32x4;    // 16B load (ext-vec for nt builtins)

__device__ inline unsigned short f2bf(float f) {  // round-to-nearest-even
    unsigned int x = __float_as_uint(f);
    unsigned int r = (x + 0x7FFF + ((x >> 16) & 1)) >> 16;
    return (unsigned short)r;
}
__device__ inline float2 h2f2(unsigned int u) {   // packed half2 -> float2
    __half2 h = *(__half2*)&u;
    return make_float2(__low2float(h), __high2float(h));
}
__device__ inline unsigned int f22h2(float a, float b) {  // 2 floats -> packed half2
    __half2 h = __floats2half2_rn(a, b);
    return *(unsigned int*)&h;
}

// ---------------------------------------------------------------------------
// PASS 1 (one launch, three independent block roles -- re-fused so the MFMA
// role overlaps the scatter role again):
//  [0, SCAT)      : scatter+count into PER-XCD private arrays. Block reads its
//                   real XCC_ID (m09-verified hwreg) and atomics ONLY its own
//                   XCD's copy with WORKGROUP scope -> plain global_atomic_add
//                   executed in the XCD-local L2 (no sc1 / MALL round-trip).
//                   Correct regardless of blockIdx->XCD mapping.
//  [SCAT, +TB)    : layer1 MFMA -> UNSCALED h (fp16) in Ht.
//  [SCAT+TB, end) : bf16-pack W2..A4b into wpAll[8192..].
__global__ __launch_bounds__(256) void pass1_kernel(
    const float* __restrict__ x, const int* __restrict__ src, const int* __restrict__ dst,
    const float* __restrict__ W1, const float* __restrict__ b1,
    const float* W2, const float* A2a, const float* A2b,
    const float* W3, const float* A3a, const float* A3b,
    const float* W4, const float* A4a, const float* A4b,
    int* __restrict__ cnt8, unsigned short* __restrict__ srcAp8,
    unsigned short* __restrict__ wp, __half* __restrict__ Ht) {
    int tid = threadIdx.x;

    if (blockIdx.x < SCAT) {                      // ---- per-XCD scatter ----
        int xcc;
        asm volatile("s_getreg_b32 %0, hwreg(HW_REG_XCC_ID)" : "=s"(xcc));
        xcc &= (NXCD - 1);
        int* mycnt = cnt8 + xcc * N_NODES;
        unsigned short* myAp = srcAp8 + (size_t)xcc * N_NODES * SUBCAP;
        for (int e = blockIdx.x * 256 + tid; e < N_EDGES; e += SCAT * 256) {
            int d = dst[e];
            int pos = __hip_atomic_fetch_add(&mycnt[d], 1, __ATOMIC_RELAXED,
                                             __HIP_MEMORY_SCOPE_WORKGROUP);
            if (pos < SUBCAP) myAp[d * SUBCAP + pos] = (unsigned short)src[e];
        }
        return;
    }
    if (blockIdx.x >= SCAT + TB) {                // ---- pack W2..A4b ----
        int i = 8192 + (blockIdx.x - SCAT - TB) * 256 + tid;
        if (i >= W_TOTAL) return;
        float v;
        if (i < 16384)      v = W2[i - 8192];
        else if (i < 20480) v = A2a[i - 16384];
        else if (i < 24576) v = A2b[i - 20480];
        else if (i < 32768) v = W3[i - 24576];
        else if (i < 36864) v = A3a[i - 32768];
        else if (i < 40960) v = A3b[i - 36864];
        else if (i < 49152) v = W4[i - 40960];
        else if (i < 53248) v = A4a[i - 49152];
        else                v = A4b[i - 53248];
        wp[i] = f2bf(v);
        return;
    }

    // ---- layer1: h = relu(x @ W1^T + b1) -> Ht (fp16, unscaled) ----
    int wave = ((blockIdx.x - SCAT) * 256 + tid) >> 6;
    if (wave >= NTILES) return;
    int lane = tid & 63;
    int r16 = lane & 15, quad = lane >> 4;
    int base = wave * 16;

    bf16x8 a[4];
    const float* xr = x + (size_t)(base + r16) * 128 + quad * 8;
#pragma unroll
    for (int kb = 0; kb < 4; kb++) {
        float4 f0 = *(const float4*)(xr + kb * 32);
        float4 f1 = *(const float4*)(xr + kb * 32 + 4);
        bf16x8 v;
        v[0] = (short)f2bf(f0.x); v[1] = (short)f2bf(f0.y);
        v[2] = (short)f2bf(f0.z); v[3] = (short)f2bf(f0.w);
        v[4] = (short)f2bf(f1.x); v[5] = (short)f2bf(f1.y);
        v[6] = (short)f2bf(f1.z); v[7] = (short)f2bf(f1.w);
        a[kb] = v;
    }

#pragma unroll
    for (int jt = 0; jt < 4; jt++) {
        f32x4 acc = {0.f, 0.f, 0.f, 0.f};
        const float* wr = W1 + (size_t)(jt * 16 + r16) * 128 + quad * 8;
#pragma unroll
        for (int kb = 0; kb < 4; kb++) {
            float4 g0 = *(const float4*)(wr + kb * 32);
            float4 g1 = *(const float4*)(wr + kb * 32 + 4);
            bf16x8 b;
            b[0] = (short)f2bf(g0.x); b[1] = (short)f2bf(g0.y);
            b[2] = (short)f2bf(g0.z); b[3] = (short)f2bf(g0.w);
            b[4] = (short)f2bf(g1.x); b[5] = (short)f2bf(g1.y);
            b[6] = (short)f2bf(g1.z); b[7] = (short)f2bf(g1.w);
            acc = __builtin_amdgcn_mfma_f32_16x16x32_bf16(a[kb], b, acc, 0, 0, 0);
        }
        int col = jt * 16 + r16;
        float bias = b1[col];
#pragma unroll
        for (int r = 0; r < 4; r++) {
            int row = base + quad * 4 + r;
            float v = fmaxf(acc[r] + bias, 0.f);
            Ht[(size_t)row * 64 + col] = __float2half(v);
        }
    }
}

// ---------------------------------------------------------------------------
// scale (R5: + sublist compaction): 16 threads per row.
//  - reads the 8 per-XCD counts; deg = sum (uncapped) -> isq/sdeg
//  - compacts the 8 sublists into contiguous srcC[row][0..cv), cv = min(total,64)
//    (thread sl handles half h=sl>>3 of sublist x=sl&7; writes go to a SEPARATE
//    buffer so no in-place overlap hazard)
//  - pads srcC[cv, ceil8(cv)) with ZROW; writes cnt[row] = cv
//  - As = Ht * isq (fp16); As8 = Ht * isq (fp8 e4m3 gather copy)
__global__ __launch_bounds__(256) void scale_kernel(const int* __restrict__ cnt8,
                                                    int* __restrict__ cnt,
                                                    const __half* __restrict__ Ht,
                                                    __half* __restrict__ As,
                                                    unsigned char* __restrict__ As8,
                                                    const unsigned short* __restrict__ srcAp8,
                                                    unsigned short* __restrict__ srcC,
                                                    float* __restrict__ isq,
                                                    float* __restrict__ sdeg) {
    int t = blockIdx.x * 256 + threadIdx.x;
    int row = t >> 4, sl = t & 15;
    if (row >= N_NODES) return;

    int deg = 0, total = 0;
    int cv8[NXCD];
#pragma unroll
    for (int k = 0; k < NXCD; k++) {
        int c = cnt8[k * N_NODES + row];
        deg += c;
        cv8[k] = min(c, SUBCAP);
        total += cv8[k];
    }
    int x = sl & 7, h = sl >> 3;
    int pfx = 0;
#pragma unroll
    for (int k = 0; k < NXCD; k++)
        if (k < x) pfx += cv8[k];
    int cv = min(total, ROWCAP);

    // compact: copy half h of sublist x
    int jend = min(cv8[x], h * 8 + 8);
    for (int j = h * 8; j < jend; j++) {
        int dpos = pfx + j;
        if (dpos < ROWCAP)
            srcC[(size_t)row * ROWCAP + dpos] =
                srcAp8[(size_t)x * N_NODES * SUBCAP + (size_t)row * SUBCAP + j];
    }
    // pad to the next multiple of 8 with the zero-row index
    int cvr = (cv + 7) & ~7;
    if (sl < cvr - cv) srcC[(size_t)row * ROWCAP + cv + sl] = (unsigned short)ZROW;

    float dv = fmaxf((float)deg, 1.0f);
    float is = rsqrtf(dv);
    if (sl == 0) {
        isq[row] = is;
        sdeg[row] = sqrtf(dv);
        cnt[row] = cv;
    }

    uint2 rv = *((const uint2*)(Ht + (size_t)row * 64) + sl);   // 4 halves
    float2 fa = h2f2(rv.x), fb = h2f2(rv.y);
    float s0 = fa.x * is, s1 = fa.y * is, s2 = fb.x * is, s3 = fb.y * is;
    uint2 ov;
    ov.x = f22h2(s0, s1);
    ov.y = f22h2(s2, s3);
    *((uint2*)(As + (size_t)row * 64) + sl) = ov;
    unsigned int w = __builtin_amdgcn_cvt_pk_fp8_f32(s0, s1, 0, false);
    w = __builtin_amdgcn_cvt_pk_fp8_f32(s2, s3, w, true);
    ((unsigned int*)As8)[(size_t)row * 16 + sl] = w;            // 4 fp8 bytes
}

// ---------------------------------------------------------------------------
// FUSED conv + dense, one block = 64 rows (4 MFMA tiles, wave-independent).
// conv: 16 rows x 4 feat-lanes, each lane gathers a 16B uint4 (quarter of the
//   64B fp8 row); one wave instruction covers 16 edges. Slot vectors are
//   prefetched one chunk ahead. Streaming accesses (srcC, dense-phase fp16
//   reads, fp16/fp32 stores) are NONTEMPORAL to keep per-XCD L2 resident for
//   the 3.2 MB fp8 gather array.
// dense: fp16 path -- h A-frags reconstructed as bf16(fp16*sdeg), so fp8
//   error enters ONLY through the conv half of the concat.
__global__ __launch_bounds__(256) void conv_dense_k(const __half* __restrict__ hs,
                                                    const unsigned char* __restrict__ hs8,
                                                    const int* __restrict__ cnt,
                                                    const unsigned short* __restrict__ srcC,
                                                    const float* __restrict__ isq,
                                                    const float* __restrict__ sdeg,
                                                    const unsigned short* __restrict__ wp,
                                                    const unsigned short* __restrict__ aap,
                                                    const unsigned short* __restrict__ abp,
                                                    __half* __restrict__ outs,
                                                    unsigned char* __restrict__ outs8,
                                                    float* __restrict__ outf,
                                                    int finalLayer) {
    __shared__ unsigned short clds[64][64];   // conv result (bf16), 8 KB
    int tid = threadIdx.x;
    int wv = tid >> 6;
    int lane = tid & 63;
    int t = blockIdx.x * 4 + wv;
    if (t >= NTILES) return;
    int base = t * 16;   // N_NODES % 16 == 0: all rows valid

    // ---- conv phase (no barrier: wave reads only its own clds quarter) ----
    {
        int r = lane >> 2, fl = lane & 3;      // 16 rows x 4 feat-lanes
        int row = base + r;
        int b = row * ROWCAP;
        int cv = min(cnt[row], ROWCAP);
        int cvr = (cv + 7) & ~7;               // slots [cv,cvr) = ZROW (zeros)
        f32x2 acc[8];
#pragma unroll
        for (int k = 0; k < 8; k++) acc[k] = (f32x2){0.f, 0.f};
        if (cvr) {
            u16x8 sv = __builtin_nontemporal_load((const u16x8*)(srcC + b));
            for (int i = 0; i < cvr; i += 8) {
                u16x8 svn = sv;                // prefetch next slot vector
                if (i + 8 < cvr)
                    svn = __builtin_nontemporal_load((const u16x8*)(srcC + b + i + 8));
                u32x4 rv[8];
#pragma unroll
                for (int u = 0; u < 8; u++)
                    rv[u] = *((const u32x4*)(hs8 + (size_t)(int)sv[u] * 64) + fl);
#pragma unroll
                for (int u = 0; u < 8; u++) {
                    acc[0] += __builtin_amdgcn_cvt_pk_f32_fp8(rv[u][0], false);
                    acc[1] += __builtin_amdgcn_cvt_pk_f32_fp8(rv[u][0], true);
                    acc[2] += __builtin_amdgcn_cvt_pk_f32_fp8(rv[u][1], false);
                    acc[3] += __builtin_amdgcn_cvt_pk_f32_fp8(rv[u][1], true);
                    acc[4] += __builtin_amdgcn_cvt_pk_f32_fp8(rv[u][2], false);
                    acc[5] += __builtin_amdgcn_cvt_pk_f32_fp8(rv[u][2], true);
                    acc[6] += __builtin_amdgcn_cvt_pk_f32_fp8(rv[u][3], false);
                    acc[7] += __builtin_amdgcn_cvt_pk_f32_fp8(rv[u][3], true);
                }
                sv = svn;
            }
        }
        float sc = isq[row];
        u16x8 o0, o1;
#pragma unroll
        for (int k = 0; k < 4; k++) {
            o0[2 * k]     = f2bf(acc[k][0] * sc);
            o0[2 * k + 1] = f2bf(acc[k][1] * sc);
            o1[2 * k]     = f2bf(acc[4 + k][0] * sc);
            o1[2 * k + 1] = f2bf(acc[4 + k][1] * sc);
        }
        // lane (r,fl) owns feats [fl*16, fl*16+16) of its row
        *(u16x8*)(&clds[wv * 16 + r][fl * 16]) = o0;
        *(u16x8*)(&clds[wv * 16 + r][fl * 16 + 8]) = o1;
    }

    // ---- dense phase ----
    int r16 = lane & 15, quad = lane >> 4;
    float rs = sdeg[base + r16];                 // h = hs * sqrt(deg), per A-row
    const u32x4* hp = (const u32x4*)(hs + (size_t)(base + r16) * 64);
    u32x4 raw0 = __builtin_nontemporal_load(hp + quad);      // feats quad*8 .. +8
    u32x4 raw1 = __builtin_nontemporal_load(hp + 4 + quad);  // feats 32+quad*8 .. +8
    bf16x8 ha0, ha1;
    {
        float2 f;
        f = h2f2(raw0[0]); ha0[0] = (short)f2bf(f.x * rs); ha0[1] = (short)f2bf(f.y * rs);
        f = h2f2(raw0[1]); ha0[2] = (short)f2bf(f.x * rs); ha0[3] = (short)f2bf(f.y * rs);
        f = h2f2(raw0[2]); ha0[4] = (short)f2bf(f.x * rs); ha0[5] = (short)f2bf(f.y * rs);
        f = h2f2(raw0[3]); ha0[6] = (short)f2bf(f.x * rs); ha0[7] = (short)f2bf(f.y * rs);
        f = h2f2(raw1[0]); ha1[0] = (short)f2bf(f.x * rs); ha1[1] = (short)f2bf(f.y * rs);
        f = h2f2(raw1[1]); ha1[2] = (short)f2bf(f.x * rs); ha1[3] = (short)f2bf(f.y * rs);
        f = h2f2(raw1[2]); ha1[4] = (short)f2bf(f.x * rs); ha1[5] = (short)f2bf(f.y * rs);
        f = h2f2(raw1[3]); ha1[6] = (short)f2bf(f.x * rs); ha1[7] = (short)f2bf(f.y * rs);
    }
    bf16x8 ca0 = *(const bf16x8*)(&clds[wv * 16 + r16][quad * 8]);
    bf16x8 ca1 = *(const bf16x8*)(&clds[wv * 16 + r16][32 + quad * 8]);

    float isq4[4];
    if (!finalLayer) {
#pragma unroll
        for (int r = 0; r < 4; r++) isq4[r] = isq[base + quad * 4 + r];
    }

#pragma unroll
    for (int jt = 0; jt < 4; jt++) {
        const unsigned short* wr = wp + (size_t)(jt * 16 + r16) * 128 + quad * 8;
        const unsigned short* ar = aap + (size_t)(jt * 16 + r16) * 64 + quad * 8;
        const unsigned short* br = abp + (size_t)(jt * 16 + r16) * 64 + quad * 8;
        f32x4 P = {0.f, 0.f, 0.f, 0.f};
        f32x4 Q = {0.f, 0.f, 0.f, 0.f};
        f32x4 R = {0.f, 0.f, 0.f, 0.f};
        P = __builtin_amdgcn_mfma_f32_16x16x32_bf16(ha0, *(const bf16x8*)(wr), P, 0, 0, 0);
        P = __builtin_amdgcn_mfma_f32_16x16x32_bf16(ha1, *(const bf16x8*)(wr + 32), P, 0, 0, 0);
        P = __builtin_amdgcn_mfma_f32_16x16x32_bf16(ca0, *(const bf16x8*)(wr + 64), P, 0, 0, 0);
        P = __builtin_amdgcn_mfma_f32_16x16x32_bf16(ca1, *(const bf16x8*)(wr + 96), P, 0, 0, 0);
        Q = __builtin_amdgcn_mfma_f32_16x16x32_bf16(ha0, *(const bf16x8*)(ar), Q, 0, 0, 0);
        Q = __builtin_amdgcn_mfma_f32_16x16x32_bf16(ha1, *(const bf16x8*)(ar + 32), Q, 0, 0, 0);
        R = __builtin_amdgcn_mfma_f32_16x16x32_bf16(ha0, *(const bf16x8*)(br), R, 0, 0, 0);
        R = __builtin_amdgcn_mfma_f32_16x16x32_bf16(ha1, *(const bf16x8*)(br + 32), R, 0, 0, 0);
        int col = jt * 16 + r16;
#pragma unroll
        for (int r = 0; r < 4; r++) {
            int row = base + quad * 4 + r;
            float v = fmaxf(P[r] + Q[r] * R[r], 0.f);
            if (finalLayer) {
                __builtin_nontemporal_store(v, &outf[(size_t)row * 64 + col]);
            } else {
                float vs = v * isq4[r];
                __half hv = __float2half(vs);
                __builtin_nontemporal_store(*(unsigned short*)&hv,
                                            (unsigned short*)outs + (size_t)row * 64 + col);
                unsigned int pb = __builtin_amdgcn_cvt_pk_fp8_f32(vs, vs, 0, false);
                outs8[(size_t)row * 64 + col] = (unsigned char)pb;  // cached: next layer gathers it
            }
        }
    }
}

// ---------------------------------------------------------------------------
extern "C" void kernel_launch(void* const* d_in, const int* in_sizes, int n_in,
                              void* d_out, int out_size, void* d_ws, size_t ws_size,
                              hipStream_t stream) {
    const float* x = (const float*)d_in[0];
    const int* edges = (const int*)d_in[1];
    const float* W1 = (const float*)d_in[2];
    const float* b1 = (const float*)d_in[3];
    const float* W2 = (const float*)d_in[4];
    const float* A2a = (const float*)d_in[5];
    const float* A2b = (const float*)d_in[6];
    const float* W3 = (const float*)d_in[7];
    const float* A3a = (const float*)d_in[8];
    const float* A3b = (const float*)d_in[9];
    const float* W4 = (const float*)d_in[10];
    const float* A4a = (const float*)d_in[11];
    const float* A4b = (const float*)d_in[12];
    float* out = (float*)d_out;

    const int* src = edges;
    const int* dst = edges + N_EDGES;

    char* p = (char*)d_ws;
    auto alloc = [&](size_t bytes) {
        char* r = p;
        p += (bytes + 255) & ~(size_t)255;
        return r;
    };
    int* cnt8             = (int*)alloc((size_t)NXCD * N_NODES * 4);           // per-XCD counters
    int* cnt              = (int*)alloc(N_NODES * 4);                          // compacted counts
    float* isq            = (float*)alloc(N_NODES * 4);
    float* sdeg           = (float*)alloc(N_NODES * 4);
    unsigned short* srcAp8= (unsigned short*)alloc((size_t)NXCD * N_NODES * SUBCAP * 2);
    unsigned short* srcC  = (unsigned short*)alloc((size_t)N_NODES * ROWCAP * 2);
    unsigned short* wpAll = (unsigned short*)alloc(W_TOTAL * 2);
    __half* Ht            = (__half*)alloc((size_t)N_NODES * 64 * 2);
    __half* As            = (__half*)alloc((size_t)N_NODES * 64 * 2);
    __half* Bs            = (__half*)alloc((size_t)N_NODES * 64 * 2);
    unsigned char* As8    = (unsigned char*)alloc((size_t)(N_NODES + 1) * 64);  // +zero row
    unsigned char* Bs8    = (unsigned char*)alloc((size_t)(N_NODES + 1) * 64);

    const unsigned short* W2p  = wpAll + 8192;
    const unsigned short* A2ap = wpAll + 16384;
    const unsigned short* A2bp = wpAll + 20480;
    const unsigned short* W3p  = wpAll + 24576;
    const unsigned short* A3ap = wpAll + 32768;
    const unsigned short* A3bp = wpAll + 36864;
    const unsigned short* W4p  = wpAll + 40960;
    const unsigned short* A4ap = wpAll + 49152;
    const unsigned short* A4bp = wpAll + 53248;

    hipMemsetAsync(cnt8, 0, (size_t)NXCD * N_NODES * 4, stream);
    hipMemsetAsync(As8 + (size_t)ZROW * 64, 0, 64, stream);   // zero pad-row
    hipMemsetAsync(Bs8 + (size_t)ZROW * 64, 0, 64, stream);

    // ---- pass 1: per-XCD scatter || layer1 || weight pack ----
    pass1_kernel<<<SCAT + TB + WB2, 256, 0, stream>>>(
        x, src, dst, W1, b1, W2, A2a, A2b, W3, A3a, A3b, W4, A4a, A4b,
        cnt8, srcAp8, wpAll, Ht);

    // ---- scale: sublist compaction + isq/sdeg + As/As8 = Ht*isq ----
    scale_kernel<<<(N_NODES * 16 + 255) / 256, 256, 0, stream>>>(
        cnt8, cnt, Ht, As, As8, srcAp8, srcC, isq, sdeg);

    // ---- layer 2: As -> Bs ----
    conv_dense_k<<<TB, 256, 0, stream>>>(As, As8, cnt, srcC, isq, sdeg,
                                         W2p, A2ap, A2bp, Bs, Bs8, nullptr, 0);
    // ---- layer 3: Bs -> As ----
    conv_dense_k<<<TB, 256, 0, stream>>>(Bs, Bs8, cnt, srcC, isq, sdeg,
                                         W3p, A3ap, A3bp, As, As8, nullptr, 0);
    // ---- layer 4: As -> out (fp32) ----
    conv_dense_k<<<TB, 256, 0, stream>>>(As, As8, cnt, srcC, isq, sdeg,
                                         W4p, A4ap, A4bp, nullptr, nullptr, out, 1);
}

// Round 7
// 226.860 us; speedup vs baseline: 1.1015x; 1.0293x over previous
//
#include <hip/hip_runtime.h>
#include <hip/hip_bf16.h>
#include <hip/hip_fp16.h>

#define N_NODES 50000
#define N_EDGES 800000
#define NTILES 3125        // N_NODES / 16
#define W_TOTAL 57344      // packed bf16 weight elements (W1 slot unused)
#define WB2 192            // pack blocks (W2..A4b = 49152 elems)
#define TB 782             // layer1/dense MFMA blocks (4 waves each)
#define ROWCAP 64          // padded-CSR slots per node (deg mean 16, 12-sigma safe)
#define ZROW N_NODES       // index of the all-zero fp8 row used for slot padding

#define NBKT 200           // dst-range buckets
#define BKT_NODES 250      // nodes per bucket (200*250 = 50000)
#define BKT_CAP 4400       // edges per bucket capacity (mean 4000, +6.3 sigma)
#define ABLK 256           // bin blocks (phase A)
#define ACH ((N_EDGES + ABLK - 1) / ABLK)   // 3125 edges per bin block

typedef __attribute__((ext_vector_type(8))) short bf16x8;          // MFMA A/B frag
typedef __attribute__((ext_vector_type(4))) float f32x4;           // MFMA C/D frag
typedef __attribute__((ext_vector_type(2))) float f32x2;           // packed f32 pair
typedef __attribute__((ext_vector_type(8))) unsigned short u16x8;  // 16B load/store
typedef __attribute__((ext_vector_type(4))) unsigned int u32x4;    // 16B load (ext-vec for nt builtins)

__device__ inline unsigned short f2bf(float f) {  // round-to-nearest-even
    unsigned int x = __float_as_uint(f);
    unsigned int r = (x + 0x7FFF + ((x >> 16) & 1)) >> 16;
    return (unsigned short)r;
}
__device__ inline float2 h2f2(unsigned int u) {   // packed half2 -> float2
    __half2 h = *(__half2*)&u;
    return make_float2(__low2float(h), __high2float(h));
}
__device__ inline unsigned int f22h2(float a, float b) {  // 2 floats -> packed half2
    __half2 h = __floats2half2_rn(a, b);
    return *(unsigned int*)&h;
}

// ---------------------------------------------------------------------------
// PASS A (one launch, three independent block roles):
//  [0, ABLK)        : edge BINNING by dst-range. Per-bucket counts in LDS
//                     (LDS atomics), ONE global atomic per (block,bucket) to
//                     reserve a run (~51K global atomics vs 800K per-edge),
//                     then packed (dl<<16|src) writes into per-bucket runs --
//                     ~200 hot L2 runs instead of 800K isolated line dirties.
//  [ABLK, +TB)      : layer1 MFMA -> UNSCALED h (fp16) in Ht.
//  [ABLK+TB, end)   : bf16-pack W2..A4b into wpAll[8192..].
__global__ __launch_bounds__(256) void passA_kernel(
    const float* __restrict__ x, const int* __restrict__ src, const int* __restrict__ dst,
    const float* __restrict__ W1, const float* __restrict__ b1,
    const float* W2, const float* A2a, const float* A2b,
    const float* W3, const float* A3a, const float* A3b,
    const float* W4, const float* A4a, const float* A4b,
    int* __restrict__ bucketCnt, unsigned int* __restrict__ bktArr,
    unsigned short* __restrict__ wp, __half* __restrict__ Ht) {
    int tid = threadIdx.x;

    if (blockIdx.x < ABLK) {                      // ---- bin edges ----
        __shared__ int hist[NBKT];
        __shared__ int gbase[NBKT];
        __shared__ int hoff[NBKT];
        if (tid < NBKT) { hist[tid] = 0; hoff[tid] = 0; }
        __syncthreads();
        int e0 = blockIdx.x * ACH;
        int e1 = min(e0 + ACH, N_EDGES);
        for (int e = e0 + tid; e < e1; e += 256)
            atomicAdd(&hist[dst[e] / BKT_NODES], 1);
        __syncthreads();
        if (tid < NBKT) {
            int h = hist[tid];
            gbase[tid] = h ? atomicAdd(&bucketCnt[tid], h) : 0;
        }
        __syncthreads();
        for (int e = e0 + tid; e < e1; e += 256) {
            int d = dst[e];
            int b = d / BKT_NODES;
            int pos = gbase[b] + atomicAdd(&hoff[b], 1);
            if (pos < BKT_CAP)
                bktArr[(size_t)b * BKT_CAP + pos] =
                    ((unsigned int)(d - b * BKT_NODES) << 16) | (unsigned int)src[e];
        }
        return;
    }
    if (blockIdx.x >= ABLK + TB) {                // ---- pack W2..A4b ----
        int i = 8192 + (blockIdx.x - ABLK - TB) * 256 + tid;
        if (i >= W_TOTAL) return;
        float v;
        if (i < 16384)      v = W2[i - 8192];
        else if (i < 20480) v = A2a[i - 16384];
        else if (i < 24576) v = A2b[i - 20480];
        else if (i < 32768) v = W3[i - 24576];
        else if (i < 36864) v = A3a[i - 32768];
        else if (i < 40960) v = A3b[i - 36864];
        else if (i < 49152) v = W4[i - 40960];
        else if (i < 53248) v = A4a[i - 49152];
        else                v = A4b[i - 53248];
        wp[i] = f2bf(v);
        return;
    }

    // ---- layer1: h = relu(x @ W1^T + b1) -> Ht (fp16, unscaled) ----
    int wave = ((blockIdx.x - ABLK) * 256 + tid) >> 6;
    if (wave >= NTILES) return;
    int lane = tid & 63;
    int r16 = lane & 15, quad = lane >> 4;
    int base = wave * 16;

    bf16x8 a[4];
    const float* xr = x + (size_t)(base + r16) * 128 + quad * 8;
#pragma unroll
    for (int kb = 0; kb < 4; kb++) {
        float4 f0 = *(const float4*)(xr + kb * 32);
        float4 f1 = *(const float4*)(xr + kb * 32 + 4);
        bf16x8 v;
        v[0] = (short)f2bf(f0.x); v[1] = (short)f2bf(f0.y);
        v[2] = (short)f2bf(f0.z); v[3] = (short)f2bf(f0.w);
        v[4] = (short)f2bf(f1.x); v[5] = (short)f2bf(f1.y);
        v[6] = (short)f2bf(f1.z); v[7] = (short)f2bf(f1.w);
        a[kb] = v;
    }

#pragma unroll
    for (int jt = 0; jt < 4; jt++) {
        f32x4 acc = {0.f, 0.f, 0.f, 0.f};
        const float* wr = W1 + (size_t)(jt * 16 + r16) * 128 + quad * 8;
#pragma unroll
        for (int kb = 0; kb < 4; kb++) {
            float4 g0 = *(const float4*)(wr + kb * 32);
            float4 g1 = *(const float4*)(wr + kb * 32 + 4);
            bf16x8 b;
            b[0] = (short)f2bf(g0.x); b[1] = (short)f2bf(g0.y);
            b[2] = (short)f2bf(g0.z); b[3] = (short)f2bf(g0.w);
            b[4] = (short)f2bf(g1.x); b[5] = (short)f2bf(g1.y);
            b[6] = (short)f2bf(g1.z); b[7] = (short)f2bf(g1.w);
            acc = __builtin_amdgcn_mfma_f32_16x16x32_bf16(a[kb], b, acc, 0, 0, 0);
        }
        int col = jt * 16 + r16;
        float bias = b1[col];
#pragma unroll
        for (int r = 0; r < 4; r++) {
            int row = base + quad * 4 + r;
            float v = fmaxf(acc[r] + bias, 0.f);
            Ht[(size_t)row * 64 + col] = __float2half(v);
        }
    }
}

// ---------------------------------------------------------------------------
// PASS B: per-bucket padded-CSR build. One block per bucket; slot assignment
// via LDS atomics (250 counters, 1 KB); scattered 2B stores confined to the
// bucket's 32 KB srcAp region (L2-resident -> ~compulsory writeback only).
// Also writes cnt[row] = FULL degree and ZROW-pads slots [cv, ceil8(cv)).
__global__ __launch_bounds__(256) void csr_k(const int* __restrict__ bucketCnt,
                                             const unsigned int* __restrict__ bktArr,
                                             unsigned short* __restrict__ srcAp,
                                             int* __restrict__ cnt) {
    __shared__ int lcnt[BKT_NODES];
    int b = blockIdx.x, tid = threadIdx.x;
    if (tid < BKT_NODES) lcnt[tid] = 0;
    __syncthreads();
    int n = min(bucketCnt[b], BKT_CAP);
    int rowbase = b * BKT_NODES;
    const unsigned int* arr = bktArr + (size_t)b * BKT_CAP;
    for (int i = tid; i < n; i += 256) {
        unsigned int u = arr[i];
        int dl = (int)(u >> 16);
        int pos = atomicAdd(&lcnt[dl], 1);
        if (pos < ROWCAP)
            srcAp[(size_t)(rowbase + dl) * ROWCAP + pos] = (unsigned short)(u & 0xFFFF);
    }
    __syncthreads();
    if (tid < BKT_NODES) {
        int deg = lcnt[tid];
        int cv = min(deg, ROWCAP);
        int cvr = (cv + 7) & ~7;
        for (int j = cv; j < cvr; j++)
            srcAp[(size_t)(rowbase + tid) * ROWCAP + j] = (unsigned short)ZROW;
        cnt[rowbase + tid] = deg;   // FULL degree (conv mins it; scale uses raw)
    }
}

// ---------------------------------------------------------------------------
// scale: isq/sdeg from cnt (full degree); As = Ht * isq (fp16); As8 = fp8
// e4m3 gather copy. 16 threads per row. (CSR padding is done in csr_k.)
__global__ __launch_bounds__(256) void scale_kernel(const int* __restrict__ cnt,
                                                    const __half* __restrict__ Ht,
                                                    __half* __restrict__ As,
                                                    unsigned char* __restrict__ As8,
                                                    float* __restrict__ isq,
                                                    float* __restrict__ sdeg) {
    int t = blockIdx.x * 256 + threadIdx.x;
    int row = t >> 4, sl = t & 15;
    if (row >= N_NODES) return;
    float dv = fmaxf((float)cnt[row], 1.0f);
    float is = rsqrtf(dv);
    if (sl == 0) {
        isq[row] = is;
        sdeg[row] = sqrtf(dv);
    }
    uint2 rv = *((const uint2*)(Ht + (size_t)row * 64) + sl);   // 4 halves
    float2 fa = h2f2(rv.x), fb = h2f2(rv.y);
    float s0 = fa.x * is, s1 = fa.y * is, s2 = fb.x * is, s3 = fb.y * is;
    uint2 ov;
    ov.x = f22h2(s0, s1);
    ov.y = f22h2(s2, s3);
    *((uint2*)(As + (size_t)row * 64) + sl) = ov;
    unsigned int w = __builtin_amdgcn_cvt_pk_fp8_f32(s0, s1, 0, false);
    w = __builtin_amdgcn_cvt_pk_fp8_f32(s2, s3, w, true);
    ((unsigned int*)As8)[(size_t)row * 16 + sl] = w;            // 4 fp8 bytes
}

// ---------------------------------------------------------------------------
// FUSED conv + dense, one block = 64 rows (4 MFMA tiles, wave-independent).
// conv: 16 rows x 4 feat-lanes, each lane gathers a 16B uint4 (quarter of the
//   64B fp8 row); one wave instruction covers 16 edges. Slot vectors are
//   prefetched one chunk ahead. Streaming accesses (srcAp, dense-phase fp16
//   reads, fp16/fp32 stores) are NONTEMPORAL to keep per-XCD L2 resident for
//   the 3.2 MB fp8 gather array.
// dense: fp16 path -- h A-frags reconstructed as bf16(fp16*sdeg), so fp8
//   error enters ONLY through the conv half of the concat.
__global__ __launch_bounds__(256) void conv_dense_k(const __half* __restrict__ hs,
                                                    const unsigned char* __restrict__ hs8,
                                                    const int* __restrict__ cnt,
                                                    const unsigned short* __restrict__ srcAp,
                                                    const float* __restrict__ isq,
                                                    const float* __restrict__ sdeg,
                                                    const unsigned short* __restrict__ wp,
                                                    const unsigned short* __restrict__ aap,
                                                    const unsigned short* __restrict__ abp,
                                                    __half* __restrict__ outs,
                                                    unsigned char* __restrict__ outs8,
                                                    float* __restrict__ outf,
                                                    int finalLayer) {
    __shared__ unsigned short clds[64][64];   // conv result (bf16), 8 KB
    int tid = threadIdx.x;
    int wv = tid >> 6;
    int lane = tid & 63;
    int t = blockIdx.x * 4 + wv;
    if (t >= NTILES) return;
    int base = t * 16;   // N_NODES % 16 == 0: all rows valid

    // ---- conv phase (no barrier: wave reads only its own clds quarter) ----
    {
        int r = lane >> 2, fl = lane & 3;      // 16 rows x 4 feat-lanes
        int row = base + r;
        int b = row * ROWCAP;
        int cv = min(cnt[row], ROWCAP);
        int cvr = (cv + 7) & ~7;               // slots [cv,cvr) = ZROW (zeros)
        f32x2 acc[8];
#pragma unroll
        for (int k = 0; k < 8; k++) acc[k] = (f32x2){0.f, 0.f};
        if (cvr) {
            u16x8 sv = __builtin_nontemporal_load((const u16x8*)(srcAp + b));
            for (int i = 0; i < cvr; i += 8) {
                u16x8 svn = sv;                // prefetch next slot vector
                if (i + 8 < cvr)
                    svn = __builtin_nontemporal_load((const u16x8*)(srcAp + b + i + 8));
                u32x4 rv[8];
#pragma unroll
                for (int u = 0; u < 8; u++)
                    rv[u] = *((const u32x4*)(hs8 + (size_t)(int)sv[u] * 64) + fl);
#pragma unroll
                for (int u = 0; u < 8; u++) {
                    acc[0] += __builtin_amdgcn_cvt_pk_f32_fp8(rv[u][0], false);
                    acc[1] += __builtin_amdgcn_cvt_pk_f32_fp8(rv[u][0], true);
                    acc[2] += __builtin_amdgcn_cvt_pk_f32_fp8(rv[u][1], false);
                    acc[3] += __builtin_amdgcn_cvt_pk_f32_fp8(rv[u][1], true);
                    acc[4] += __builtin_amdgcn_cvt_pk_f32_fp8(rv[u][2], false);
                    acc[5] += __builtin_amdgcn_cvt_pk_f32_fp8(rv[u][2], true);
                    acc[6] += __builtin_amdgcn_cvt_pk_f32_fp8(rv[u][3], false);
                    acc[7] += __builtin_amdgcn_cvt_pk_f32_fp8(rv[u][3], true);
                }
                sv = svn;
            }
        }
        float sc = isq[row];
        u16x8 o0, o1;
#pragma unroll
        for (int k = 0; k < 4; k++) {
            o0[2 * k]     = f2bf(acc[k][0] * sc);
            o0[2 * k + 1] = f2bf(acc[k][1] * sc);
            o1[2 * k]     = f2bf(acc[4 + k][0] * sc);
            o1[2 * k + 1] = f2bf(acc[4 + k][1] * sc);
        }
        // lane (r,fl) owns feats [fl*16, fl*16+16) of its row
        *(u16x8*)(&clds[wv * 16 + r][fl * 16]) = o0;
        *(u16x8*)(&clds[wv * 16 + r][fl * 16 + 8]) = o1;
    }

    // ---- dense phase ----
    int r16 = lane & 15, quad = lane >> 4;
    float rs = sdeg[base + r16];                 // h = hs * sqrt(deg), per A-row
    const u32x4* hp = (const u32x4*)(hs + (size_t)(base + r16) * 64);
    u32x4 raw0 = __builtin_nontemporal_load(hp + quad);      // feats quad*8 .. +8
    u32x4 raw1 = __builtin_nontemporal_load(hp + 4 + quad);  // feats 32+quad*8 .. +8
    bf16x8 ha0, ha1;
    {
        float2 f;
        f = h2f2(raw0[0]); ha0[0] = (short)f2bf(f.x * rs); ha0[1] = (short)f2bf(f.y * rs);
        f = h2f2(raw0[1]); ha0[2] = (short)f2bf(f.x * rs); ha0[3] = (short)f2bf(f.y * rs);
        f = h2f2(raw0[2]); ha0[4] = (short)f2bf(f.x * rs); ha0[5] = (short)f2bf(f.y * rs);
        f = h2f2(raw0[3]); ha0[6] = (short)f2bf(f.x * rs); ha0[7] = (short)f2bf(f.y * rs);
        f = h2f2(raw1[0]); ha1[0] = (short)f2bf(f.x * rs); ha1[1] = (short)f2bf(f.y * rs);
        f = h2f2(raw1[1]); ha1[2] = (short)f2bf(f.x * rs); ha1[3] = (short)f2bf(f.y * rs);
        f = h2f2(raw1[2]); ha1[4] = (short)f2bf(f.x * rs); ha1[5] = (short)f2bf(f.y * rs);
        f = h2f2(raw1[3]); ha1[6] = (short)f2bf(f.x * rs); ha1[7] = (short)f2bf(f.y * rs);
    }
    bf16x8 ca0 = *(const bf16x8*)(&clds[wv * 16 + r16][quad * 8]);
    bf16x8 ca1 = *(const bf16x8*)(&clds[wv * 16 + r16][32 + quad * 8]);

    float isq4[4];
    if (!finalLayer) {
#pragma unroll
        for (int r = 0; r < 4; r++) isq4[r] = isq[base + quad * 4 + r];
    }

#pragma unroll
    for (int jt = 0; jt < 4; jt++) {
        const unsigned short* wr = wp + (size_t)(jt * 16 + r16) * 128 + quad * 8;
        const unsigned short* ar = aap + (size_t)(jt * 16 + r16) * 64 + quad * 8;
        const unsigned short* br = abp + (size_t)(jt * 16 + r16) * 64 + quad * 8;
        f32x4 P = {0.f, 0.f, 0.f, 0.f};
        f32x4 Q = {0.f, 0.f, 0.f, 0.f};
        f32x4 R = {0.f, 0.f, 0.f, 0.f};
        P = __builtin_amdgcn_mfma_f32_16x16x32_bf16(ha0, *(const bf16x8*)(wr), P, 0, 0, 0);
        P = __builtin_amdgcn_mfma_f32_16x16x32_bf16(ha1, *(const bf16x8*)(wr + 32), P, 0, 0, 0);
        P = __builtin_amdgcn_mfma_f32_16x16x32_bf16(ca0, *(const bf16x8*)(wr + 64), P, 0, 0, 0);
        P = __builtin_amdgcn_mfma_f32_16x16x32_bf16(ca1, *(const bf16x8*)(wr + 96), P, 0, 0, 0);
        Q = __builtin_amdgcn_mfma_f32_16x16x32_bf16(ha0, *(const bf16x8*)(ar), Q, 0, 0, 0);
        Q = __builtin_amdgcn_mfma_f32_16x16x32_bf16(ha1, *(const bf16x8*)(ar + 32), Q, 0, 0, 0);
        R = __builtin_amdgcn_mfma_f32_16x16x32_bf16(ha0, *(const bf16x8*)(br), R, 0, 0, 0);
        R = __builtin_amdgcn_mfma_f32_16x16x32_bf16(ha1, *(const bf16x8*)(br + 32), R, 0, 0, 0);
        int col = jt * 16 + r16;
#pragma unroll
        for (int r = 0; r < 4; r++) {
            int row = base + quad * 4 + r;
            float v = fmaxf(P[r] + Q[r] * R[r], 0.f);
            if (finalLayer) {
                __builtin_nontemporal_store(v, &outf[(size_t)row * 64 + col]);
            } else {
                float vs = v * isq4[r];
                __half hv = __float2half(vs);
                __builtin_nontemporal_store(*(unsigned short*)&hv,
                                            (unsigned short*)outs + (size_t)row * 64 + col);
                unsigned int pb = __builtin_amdgcn_cvt_pk_fp8_f32(vs, vs, 0, false);
                outs8[(size_t)row * 64 + col] = (unsigned char)pb;  // cached: next layer gathers it
            }
        }
    }
}

// ---------------------------------------------------------------------------
extern "C" void kernel_launch(void* const* d_in, const int* in_sizes, int n_in,
                              void* d_out, int out_size, void* d_ws, size_t ws_size,
                              hipStream_t stream) {
    const float* x = (const float*)d_in[0];
    const int* edges = (const int*)d_in[1];
    const float* W1 = (const float*)d_in[2];
    const float* b1 = (const float*)d_in[3];
    const float* W2 = (const float*)d_in[4];
    const float* A2a = (const float*)d_in[5];
    const float* A2b = (const float*)d_in[6];
    const float* W3 = (const float*)d_in[7];
    const float* A3a = (const float*)d_in[8];
    const float* A3b = (const float*)d_in[9];
    const float* W4 = (const float*)d_in[10];
    const float* A4a = (const float*)d_in[11];
    const float* A4b = (const float*)d_in[12];
    float* out = (float*)d_out;

    const int* src = edges;
    const int* dst = edges + N_EDGES;

    char* p = (char*)d_ws;
    auto alloc = [&](size_t bytes) {
        char* r = p;
        p += (bytes + 255) & ~(size_t)255;
        return r;
    };
    int* bucketCnt        = (int*)alloc(NBKT * 4);
    unsigned int* bktArr  = (unsigned int*)alloc((size_t)NBKT * BKT_CAP * 4);
    int* cnt              = (int*)alloc(N_NODES * 4);                 // full degree
    float* isq            = (float*)alloc(N_NODES * 4);
    float* sdeg           = (float*)alloc(N_NODES * 4);
    unsigned short* srcAp = (unsigned short*)alloc((size_t)N_NODES * ROWCAP * 2);
    unsigned short* wpAll = (unsigned short*)alloc(W_TOTAL * 2);
    __half* Ht            = (__half*)alloc((size_t)N_NODES * 64 * 2);
    __half* As            = (__half*)alloc((size_t)N_NODES * 64 * 2);
    __half* Bs            = (__half*)alloc((size_t)N_NODES * 64 * 2);
    unsigned char* As8    = (unsigned char*)alloc((size_t)(N_NODES + 1) * 64);  // +zero row
    unsigned char* Bs8    = (unsigned char*)alloc((size_t)(N_NODES + 1) * 64);

    const unsigned short* W2p  = wpAll + 8192;
    const unsigned short* A2ap = wpAll + 16384;
    const unsigned short* A2bp = wpAll + 20480;
    const unsigned short* W3p  = wpAll + 24576;
    const unsigned short* A3ap = wpAll + 32768;
    const unsigned short* A3bp = wpAll + 36864;
    const unsigned short* W4p  = wpAll + 40960;
    const unsigned short* A4ap = wpAll + 49152;
    const unsigned short* A4bp = wpAll + 53248;

    hipMemsetAsync(bucketCnt, 0, NBKT * 4, stream);
    hipMemsetAsync(As8 + (size_t)ZROW * 64, 0, 64, stream);   // zero pad-row
    hipMemsetAsync(Bs8 + (size_t)ZROW * 64, 0, 64, stream);

    // ---- pass A: bin edges || layer1 || weight pack ----
    passA_kernel<<<ABLK + TB + WB2, 256, 0, stream>>>(
        x, src, dst, W1, b1, W2, A2a, A2b, W3, A3a, A3b, W4, A4a, A4b,
        bucketCnt, bktArr, wpAll, Ht);

    // ---- pass B: per-bucket padded-CSR build (LDS atomics) ----
    csr_k<<<NBKT, 256, 0, stream>>>(bucketCnt, bktArr, srcAp, cnt);

    // ---- scale: isq/sdeg + As/As8 = Ht*isq ----
    scale_kernel<<<(N_NODES * 16 + 255) / 256, 256, 0, stream>>>(
        cnt, Ht, As, As8, isq, sdeg);

    // ---- layer 2: As -> Bs ----
    conv_dense_k<<<TB, 256, 0, stream>>>(As, As8, cnt, srcAp, isq, sdeg,
                                         W2p, A2ap, A2bp, Bs, Bs8, nullptr, 0);
    // ---- layer 3: Bs -> As ----
    conv_dense_k<<<TB, 256, 0, stream>>>(Bs, Bs8, cnt, srcAp, isq, sdeg,
                                         W3p, A3ap, A3bp, As, As8, nullptr, 0);
    // ---- layer 4: As -> out (fp32) ----
    conv_dense_k<<<TB, 256, 0, stream>>>(As, As8, cnt, srcAp, isq, sdeg,
                                         W4p, A4ap, A4bp, nullptr, nullptr, out, 1);
}